// Round 1
// baseline (473.869 us; speedup 1.0000x reference)
//
#include <hip/hip_runtime.h>
#include <cstdint>
#include <cstddef>

// Problem constants (Qwen3VLMoeTextExperts): E=8, H=2048, I=768, T=B*S=4096
#define NE 8
#define NH 2048
#define NI 768
#define NT 4096
#define NK2 6144   // NE*NI : K of second GEMM

typedef __bf16 bf16x8 __attribute__((ext_vector_type(8)));
typedef float f32x4 __attribute__((ext_vector_type(4)));
typedef unsigned short u16x8 __attribute__((ext_vector_type(8)));

__device__ __forceinline__ unsigned short f2bf(float f) {
  unsigned int u = __builtin_bit_cast(unsigned int, f);
  u += 0x7fffu + ((u >> 16) & 1u);   // round-to-nearest-even
  return (unsigned short)(u >> 16);
}

// async global->LDS, 16B per lane. LDS dest must be wave-uniform base + lane*16
// (our tid-linear mapping satisfies this).
__device__ __forceinline__ void gload_lds16(const void* g, void* s) {
  __builtin_amdgcn_global_load_lds(
      (const __attribute__((address_space(1))) unsigned int*)g,
      (__attribute__((address_space(3))) unsigned int*)s, 16, 0, 0);
}

// ---------------- convert f32 -> bf16 (vectorized x8) ----------------
__global__ __launch_bounds__(256) void k_cvt(const float* __restrict__ in,
                                             unsigned short* __restrict__ out,
                                             long n) {
  long i = ((long)blockIdx.x * blockDim.x + threadIdx.x) * 8;
  if (i >= n) return;
  float4 f0 = *reinterpret_cast<const float4*>(in + i);
  float4 f1 = *reinterpret_cast<const float4*>(in + i + 4);
  u16x8 o;
  o[0] = f2bf(f0.x); o[1] = f2bf(f0.y); o[2] = f2bf(f0.z); o[3] = f2bf(f0.w);
  o[4] = f2bf(f1.x); o[5] = f2bf(f1.y); o[6] = f2bf(f1.z); o[7] = f2bf(f1.w);
  *reinterpret_cast<u16x8*>(out + i) = o;
}

// ------------- transpose + convert: out[b*oBS + c*oCS + r] = in[b][r][c] -------------
__global__ __launch_bounds__(256) void k_transpose_cvt(
    const float* __restrict__ in, unsigned short* __restrict__ out,
    int R, int C, long inBS, long outBS, int outCS) {
  __shared__ float tile[32][33];
  const int b = blockIdx.z;
  const int r0 = blockIdx.y * 32, c0 = blockIdx.x * 32;
  const int tx = threadIdx.x, ty = threadIdx.y;
  const float* ib = in + (long)b * inBS;
#pragma unroll
  for (int d = 0; d < 4; d++)
    tile[ty + d * 8][tx] = ib[(long)(r0 + ty + d * 8) * C + c0 + tx];
  __syncthreads();
#pragma unroll
  for (int d = 0; d < 4; d++) {
    int c = c0 + ty + d * 8;   // out major index
    int r = r0 + tx;           // out minor index (coalesced)
    out[(long)b * outBS + (long)c * outCS + r] = f2bf(tile[tx][ty + d * 8]);
  }
}

// ---------------- GEMM1 fused: inter[t][e*NI+n] = rw[t][e] * up * silu(gate) ----------------
// grid: (NI/64=12, NT/128=32, NE=8), block 256 (4 waves, 2x2)
__global__ __launch_bounds__(256) void k_gemm1(
    const unsigned short* __restrict__ Xb,    // [NT][NH] bf16
    const unsigned short* __restrict__ W1t,   // [NE][2*NI][NH] bf16 (n-major, k-contig)
    const float* __restrict__ rw,             // [NT][NE]
    unsigned short* __restrict__ inter) {     // [NT][NK2] bf16
  __shared__ unsigned short As[128 * 32];
  __shared__ unsigned short Bs[128 * 32];
  const int e = blockIdx.z;
  const int t0 = blockIdx.y * 128;
  const int n0 = blockIdx.x * 64;
  const int tid = threadIdx.x;
  const int lane = tid & 63;
  const int wave = tid >> 6;
  const int wr = wave >> 1, wc = wave & 1;

  const unsigned short* W1e = W1t + (size_t)e * (2 * NI) * NH;

  const int sRow = tid >> 2;        // 0..63
  const int sK = (tid & 3) * 8;     // 0,8,16,24

  f32x4 acc[4][4];
#pragma unroll
  for (int i = 0; i < 4; i++)
#pragma unroll
    for (int j = 0; j < 4; j++) acc[i][j] = (f32x4){0.f, 0.f, 0.f, 0.f};

  const int kf = (lane >> 4) * 8;
  const int rA = wr * 64 + (lane & 15);
  const int rB = wc * 32 + (lane & 15);

  for (int k0 = 0; k0 < NH; k0 += 32) {
    // stage A (128x32) and B (64 gate rows + 64 up rows, each [row][32] k-contig)
    gload_lds16(Xb + (size_t)(t0 + sRow) * NH + k0 + sK, &As[tid * 8]);
    gload_lds16(Xb + (size_t)(t0 + 64 + sRow) * NH + k0 + sK, &As[2048 + tid * 8]);
    gload_lds16(W1e + (size_t)(n0 + sRow) * NH + k0 + sK, &Bs[tid * 8]);
    gload_lds16(W1e + (size_t)(NI + n0 + sRow) * NH + k0 + sK, &Bs[2048 + tid * 8]);
    __syncthreads();   // drains vmcnt -> LDS valid

    bf16x8 a[4], b[4];
#pragma unroll
    for (int i = 0; i < 4; i++)
      a[i] = *reinterpret_cast<const bf16x8*>(&As[(rA + i * 16) * 32 + kf]);
    b[0] = *reinterpret_cast<const bf16x8*>(&Bs[(rB) * 32 + kf]);          // gate j=0
    b[1] = *reinterpret_cast<const bf16x8*>(&Bs[(rB + 16) * 32 + kf]);     // gate j=1
    b[2] = *reinterpret_cast<const bf16x8*>(&Bs[(64 + rB) * 32 + kf]);     // up   j=0
    b[3] = *reinterpret_cast<const bf16x8*>(&Bs[(64 + rB + 16) * 32 + kf]);// up   j=1
#pragma unroll
    for (int i = 0; i < 4; i++)
#pragma unroll
      for (int j = 0; j < 4; j++)
        acc[i][j] = __builtin_amdgcn_mfma_f32_16x16x32_bf16(a[i], b[j], acc[i][j], 0, 0, 0);
    __syncthreads();   // protect LDS before next stage
  }

  // epilogue: silu(gate)*up*rw -> bf16
  const int rowBase = t0 + wr * 64 + ((lane >> 4) << 2);
  float rwv[4][4];
#pragma unroll
  for (int i = 0; i < 4; i++)
#pragma unroll
    for (int r = 0; r < 4; r++)
      rwv[i][r] = rw[(size_t)(rowBase + i * 16 + r) * NE + e];

#pragma unroll
  for (int i = 0; i < 4; i++) {
#pragma unroll
    for (int j = 0; j < 2; j++) {
#pragma unroll
      for (int r = 0; r < 4; r++) {
        float g = acc[i][j][r];
        float u = acc[i][j + 2][r];
        float s = g / (1.f + __expf(-g));  // silu
        float v = rwv[i][r] * u * s;
        int t = rowBase + i * 16 + r;
        int col = n0 + wc * 32 + j * 16 + (lane & 15);
        inter[(size_t)t * NK2 + e * NI + col] = f2bf(v);
      }
    }
  }
}

// ---------------- GEMM2: out[t][h] = sum_k inter[t][k] * W2t[h][k], K=6144 ----------------
// grid: (NH/128=16, NT/128=32), block 256 (4 waves, 2x2, each 64x64)
__global__ __launch_bounds__(256) void k_gemm2(
    const unsigned short* __restrict__ inter,  // [NT][NK2] bf16
    const unsigned short* __restrict__ W2t,    // [NH][NK2] bf16
    float* __restrict__ out) {                 // [NT][NH] f32
  __shared__ unsigned short As[128 * 32];
  __shared__ unsigned short Bs[128 * 32];
  const int t0 = blockIdx.y * 128;
  const int h0 = blockIdx.x * 128;
  const int tid = threadIdx.x;
  const int lane = tid & 63;
  const int wave = tid >> 6;
  const int wr = wave >> 1, wc = wave & 1;

  const int sRow = tid >> 2;
  const int sK = (tid & 3) * 8;

  f32x4 acc[4][4];
#pragma unroll
  for (int i = 0; i < 4; i++)
#pragma unroll
    for (int j = 0; j < 4; j++) acc[i][j] = (f32x4){0.f, 0.f, 0.f, 0.f};

  const int kf = (lane >> 4) * 8;
  const int rA = wr * 64 + (lane & 15);
  const int rB = wc * 64 + (lane & 15);

  for (int k0 = 0; k0 < NK2; k0 += 32) {
    gload_lds16(inter + (size_t)(t0 + sRow) * NK2 + k0 + sK, &As[tid * 8]);
    gload_lds16(inter + (size_t)(t0 + 64 + sRow) * NK2 + k0 + sK, &As[2048 + tid * 8]);
    gload_lds16(W2t + (size_t)(h0 + sRow) * NK2 + k0 + sK, &Bs[tid * 8]);
    gload_lds16(W2t + (size_t)(h0 + 64 + sRow) * NK2 + k0 + sK, &Bs[2048 + tid * 8]);
    __syncthreads();

    bf16x8 a[4], b[4];
#pragma unroll
    for (int i = 0; i < 4; i++)
      a[i] = *reinterpret_cast<const bf16x8*>(&As[(rA + i * 16) * 32 + kf]);
#pragma unroll
    for (int j = 0; j < 4; j++)
      b[j] = *reinterpret_cast<const bf16x8*>(&Bs[(rB + j * 16) * 32 + kf]);
#pragma unroll
    for (int i = 0; i < 4; i++)
#pragma unroll
      for (int j = 0; j < 4; j++)
        acc[i][j] = __builtin_amdgcn_mfma_f32_16x16x32_bf16(a[i], b[j], acc[i][j], 0, 0, 0);
    __syncthreads();
  }

  const int rowBase = t0 + wr * 64 + ((lane >> 4) << 2);
#pragma unroll
  for (int i = 0; i < 4; i++)
#pragma unroll
    for (int j = 0; j < 4; j++)
#pragma unroll
      for (int r = 0; r < 4; r++) {
        int t = rowBase + i * 16 + r;
        int h = h0 + wc * 64 + j * 16 + (lane & 15);
        out[(size_t)t * NH + h] = acc[i][j][r];
      }
}

extern "C" void kernel_launch(void* const* d_in, const int* in_sizes, int n_in,
                              void* d_out, int out_size, void* d_ws, size_t ws_size,
                              hipStream_t stream) {
  const float* x = (const float*)d_in[0];    // [NT][NH]
  const float* rw = (const float*)d_in[1];   // [NT][NE]
  // d_in[2] router_indices: unused by reference (dense all-experts)
  const float* w1 = (const float*)d_in[3];   // [NE][NH][2*NI]
  const float* w2 = (const float*)d_in[4];   // [NE][NI][NH]
  float* out = (float*)d_out;

  char* ws = (char*)d_ws;
  // ws layout (bf16): Xb 16MB | W1t 48MB | W2t 24MB | inter 48MB  = 136 MiB
  unsigned short* Xb = (unsigned short*)ws;                               // [NT][NH]
  unsigned short* W1t = (unsigned short*)(ws + 16777216);                 // [NE][2NI][NH]
  unsigned short* W2t = (unsigned short*)(ws + 16777216 + 50331648);      // [NH][NK2]
  unsigned short* inter = (unsigned short*)(ws + 16777216 + 50331648 + 25165824); // [NT][NK2]

  // 1) convert x
  k_cvt<<<dim3((NT * NH) / (256 * 8)), dim3(256), 0, stream>>>(x, Xb, (long)NT * NH);
  // 2) W1 [E][H][2I] -> W1t [E][2I][H]
  k_transpose_cvt<<<dim3((2 * NI) / 32, NH / 32, NE), dim3(32, 8), 0, stream>>>(
      w1, W1t, NH, 2 * NI, (long)NH * 2 * NI, (long)2 * NI * NH, NH);
  // 3) W2 [E][I][H] -> W2t [H][E*I]
  k_transpose_cvt<<<dim3(NH / 32, NI / 32, NE), dim3(32, 8), 0, stream>>>(
      w2, W2t, NI, NH, (long)NI * NH, (long)NI, NK2);
  // 4) GEMM1 fused silu/up/rw -> inter
  k_gemm1<<<dim3(NI / 64, NT / 128, NE), dim3(256), 0, stream>>>(Xb, W1t, rw, inter);
  // 5) GEMM2 -> out
  k_gemm2<<<dim3(NH / 128, NT / 128), dim3(256), 0, stream>>>(inter, W2t, out);
}

// Round 2
// 378.031 us; speedup vs baseline: 1.2535x; 1.2535x over previous
//
#include <hip/hip_runtime.h>
#include <cstdint>
#include <cstddef>

// Problem constants (Qwen3VLMoeTextExperts): E=8, H=2048, I=768, T=B*S=4096
#define NE 8
#define NH 2048
#define NI 768
#define NT 4096
#define NK2 6144   // NE*NI : K of second GEMM

typedef __bf16 bf16x8 __attribute__((ext_vector_type(8)));
typedef float f32x4 __attribute__((ext_vector_type(4)));
typedef unsigned short u16x8 __attribute__((ext_vector_type(8)));

__device__ __forceinline__ unsigned short f2bf(float f) {
  unsigned int u = __builtin_bit_cast(unsigned int, f);
  u += 0x7fffu + ((u >> 16) & 1u);   // round-to-nearest-even
  return (unsigned short)(u >> 16);
}

// async global->LDS, 16B per lane (dest must be linear: base + lane*16).
__device__ __forceinline__ void gload_lds16(const void* g, void* s) {
  __builtin_amdgcn_global_load_lds(
      (const __attribute__((address_space(1))) unsigned int*)g,
      (__attribute__((address_space(3))) unsigned int*)s, 16, 0, 0);
}

// ---------------- convert f32 -> bf16 (vectorized x8) ----------------
__global__ __launch_bounds__(256) void k_cvt(const float* __restrict__ in,
                                             unsigned short* __restrict__ out,
                                             long n) {
  long i = ((long)blockIdx.x * blockDim.x + threadIdx.x) * 8;
  if (i >= n) return;
  float4 f0 = *reinterpret_cast<const float4*>(in + i);
  float4 f1 = *reinterpret_cast<const float4*>(in + i + 4);
  u16x8 o;
  o[0] = f2bf(f0.x); o[1] = f2bf(f0.y); o[2] = f2bf(f0.z); o[3] = f2bf(f0.w);
  o[4] = f2bf(f1.x); o[5] = f2bf(f1.y); o[6] = f2bf(f1.z); o[7] = f2bf(f1.w);
  *reinterpret_cast<u16x8*>(out + i) = o;
}

// ------------- transpose + convert: out[b*oBS + perm(c)*oCS + r] = in[b][r][c] -------------
// mode 0: perm = identity. mode 1 (gate_up): interleave gate/up at 16-col
// granularity: gate col c -> (c>>4)*32 + (c&15); up col c -> (c>>4)*32 + 16 + (c&15).
__global__ __launch_bounds__(256) void k_transpose_cvt(
    const float* __restrict__ in, unsigned short* __restrict__ out,
    int R, int C, long inBS, long outBS, int outCS, int mode) {
  __shared__ float tile[32][33];
  const int b = blockIdx.z;
  const int r0 = blockIdx.y * 32, c0 = blockIdx.x * 32;
  const int tx = threadIdx.x, ty = threadIdx.y;
  const float* ib = in + (long)b * inBS;
#pragma unroll
  for (int d = 0; d < 4; d++)
    tile[ty + d * 8][tx] = ib[(long)(r0 + ty + d * 8) * C + c0 + tx];
  __syncthreads();
#pragma unroll
  for (int d = 0; d < 4; d++) {
    int c = c0 + ty + d * 8;   // original out-major index
    int r = r0 + tx;           // out minor index (coalesced)
    int orow;
    if (mode == 1) {
      int z = (c >= NI) ? 1 : 0;
      int cc = c - z * NI;
      orow = ((cc >> 4) << 5) + (z << 4) + (cc & 15);
    } else {
      orow = c;
    }
    out[(long)b * outBS + (long)orow * outCS + r] = f2bf(tile[tx][ty + d * 8]);
  }
}

// ================= deep-pipelined GEMM core =================
// BM=256 (A rows), BNB=128 (B rows), BK=64. 512 threads = 8 waves (4M x 2N),
// per-wave 64x64 output. LDS: 3 buffers x (A 256x64 + B 128x64) bf16 = 144 KiB.
// Pipeline: while computing kt, stage kt+2 into buf[(kt+2)%3]; one
// s_barrier + counted vmcnt(6) per K-tile (6 gload_lds per tile per thread).
// T2: chunk swizzle c ^= (row&7), pre-swizzled on the global source side.

#define BUF_US 24576   // ushorts per buffer (48 KiB)
#define B_OFF 16384    // B region offset within buffer (ushorts)

__device__ __forceinline__ void gemm_core(
    const unsigned short* __restrict__ A, int ldA, int rowA0,
    const unsigned short* __restrict__ B, int ldB, int rowB0,
    int nkt, unsigned short* lds, f32x4 acc[4][4]) {
  const int tid = threadIdx.x;
  const int lane = tid & 63;
  const int wave = tid >> 6;
  const int wr = wave >> 1;        // 0..3 (M)
  const int wc = wave & 1;         // 0..1 (N)
  const int fr = lane & 15, fq = lane >> 4;

  // per-thread stage source offsets (global, element units) + LDS dests
  size_t sA[4]; int dA[4];
#pragma unroll
  for (int q = 0; q < 4; ++q) {
    int chunk = q * 512 + tid;       // 0..2047 over A tile (256 rows x 8 chunks)
    int row = chunk >> 3, c = chunk & 7;
    sA[q] = (size_t)(rowA0 + row) * ldA + ((c ^ (row & 7)) << 3);
    dA[q] = chunk * 8;
  }
  size_t sB[2]; int dB[2];
#pragma unroll
  for (int q = 0; q < 2; ++q) {
    int chunk = q * 512 + tid;       // 0..1023 over B tile (128 rows x 8 chunks)
    int row = chunk >> 3, c = chunk & 7;
    sB[q] = (size_t)(rowB0 + row) * ldB + ((c ^ (row & 7)) << 3);
    dB[q] = B_OFF + chunk * 8;
  }

  // LDS fragment read offsets (swizzled), [kk][frag]
  int aO[2][4], bO[2][4];
#pragma unroll
  for (int kk = 0; kk < 2; ++kk) {
#pragma unroll
    for (int i = 0; i < 4; ++i) {
      int rowA = wr * 64 + i * 16 + fr;
      aO[kk][i] = rowA * 64 + (((kk * 4 + fq) ^ (rowA & 7)) << 3);
      int rowB = wc * 64 + i * 16 + fr;
      bO[kk][i] = B_OFF + rowB * 64 + (((kk * 4 + fq) ^ (rowB & 7)) << 3);
    }
  }

#pragma unroll
  for (int i = 0; i < 4; ++i)
#pragma unroll
    for (int j = 0; j < 4; ++j) acc[i][j] = (f32x4){0.f, 0.f, 0.f, 0.f};

  // prologue: stage kt=0 -> buf0, kt=1 -> buf1
#pragma unroll
  for (int q = 0; q < 4; ++q) gload_lds16(A + sA[q], lds + dA[q]);
#pragma unroll
  for (int q = 0; q < 2; ++q) gload_lds16(B + sB[q], lds + dB[q]);
#pragma unroll
  for (int q = 0; q < 4; ++q) gload_lds16(A + sA[q] + 64, lds + BUF_US + dA[q]);
#pragma unroll
  for (int q = 0; q < 2; ++q) gload_lds16(B + sB[q] + 64, lds + BUF_US + dB[q]);

  int bi = 0;   // kt % 3
  int bs = 2;   // (kt+2) % 3
  for (int kt = 0; kt < nkt; ++kt) {
    // boundary: ensure tile kt fully landed (all waves), keep kt+1 in flight
    if (kt == nkt - 1) {
      asm volatile("s_waitcnt vmcnt(0)" ::: "memory");
    } else {
      asm volatile("s_waitcnt vmcnt(6)" ::: "memory");
    }
    __builtin_amdgcn_s_barrier();
    __builtin_amdgcn_sched_barrier(0);

    // stage kt+2 into idle buffer
    if (kt + 2 < nkt) {
      const int k0 = (kt + 2) * 64;
      unsigned short* tb = lds + bs * BUF_US;
#pragma unroll
      for (int q = 0; q < 4; ++q) gload_lds16(A + sA[q] + k0, tb + dA[q]);
#pragma unroll
      for (int q = 0; q < 2; ++q) gload_lds16(B + sB[q] + k0, tb + dB[q]);
    }

    // compute tile kt
    const unsigned short* cb = lds + bi * BUF_US;
#pragma unroll
    for (int kk = 0; kk < 2; ++kk) {
      bf16x8 a[4], b[4];
#pragma unroll
      for (int i = 0; i < 4; ++i) a[i] = *reinterpret_cast<const bf16x8*>(cb + aO[kk][i]);
#pragma unroll
      for (int j = 0; j < 4; ++j) b[j] = *reinterpret_cast<const bf16x8*>(cb + bO[kk][j]);
      __builtin_amdgcn_s_setprio(1);
#pragma unroll
      for (int i = 0; i < 4; ++i)
#pragma unroll
        for (int j = 0; j < 4; ++j)
          acc[i][j] = __builtin_amdgcn_mfma_f32_16x16x32_bf16(a[i], b[j], acc[i][j], 0, 0, 0);
      __builtin_amdgcn_s_setprio(0);
    }

    bi = (bi == 2) ? 0 : bi + 1;
    bs = (bs == 2) ? 0 : bs + 1;
  }
}

// ---------------- GEMM1 fused: inter[t][e*NI+col] = rw[t][e] * up * silu(gate) ----------------
// W1t rows are gate/up interleaved at 16: each wave's j=0,2 frags are gate,
// j=1,3 are up for the same 16 inter cols -> silu fusion is register-local.
// grid: (1536/128=12, NT/256=16, NE=8), block 512
__global__ __launch_bounds__(512, 2) void k_gemm1(
    const unsigned short* __restrict__ Xb,    // [NT][NH] bf16
    const unsigned short* __restrict__ W1t,   // [NE][1536(perm)][NH] bf16
    const float* __restrict__ rw,             // [NT][NE]
    unsigned short* __restrict__ inter) {     // [NT][NK2] bf16
  __shared__ unsigned short lds[3 * BUF_US];
  const int e = blockIdx.z;
  const int t0 = blockIdx.y * 256;
  const int bn = blockIdx.x;       // 128 B-rows -> 64 inter cols
  f32x4 acc[4][4];
  gemm_core(Xb, NH, t0, W1t + (size_t)e * (2 * NI) * NH, NH, bn * 128,
            NH / 64, lds, acc);

  const int tid = threadIdx.x, lane = tid & 63, wave = tid >> 6;
  const int wr = wave >> 1, wc = wave & 1, fr = lane & 15, fq = lane >> 4;
  const int rowBase = t0 + wr * 64 + fq * 4;
#pragma unroll
  for (int i = 0; i < 4; ++i) {
#pragma unroll
    for (int r = 0; r < 4; ++r) {
      const int t = rowBase + i * 16 + r;
      const float rwv = rw[(size_t)t * NE + e];
#pragma unroll
      for (int p = 0; p < 2; ++p) {
        float g = acc[i][2 * p][r];       // gate
        float u = acc[i][2 * p + 1][r];   // up
        float s = g / (1.f + __expf(-g)); // silu
        int col = bn * 64 + wc * 32 + p * 16 + fr;
        inter[(size_t)t * NK2 + e * NI + col] = f2bf(rwv * u * s);
      }
    }
  }
}

// ---------------- GEMM2: out[t][h] = sum_k inter[t][k] * W2t[h][k], K=6144 ----------------
// grid: (NH/128=16, NT/256=16), block 512
__global__ __launch_bounds__(512, 2) void k_gemm2(
    const unsigned short* __restrict__ inter,  // [NT][NK2] bf16
    const unsigned short* __restrict__ W2t,    // [NH][NK2] bf16
    float* __restrict__ out) {                 // [NT][NH] f32
  __shared__ unsigned short lds[3 * BUF_US];
  const int t0 = blockIdx.y * 256;
  const int h0 = blockIdx.x * 128;
  f32x4 acc[4][4];
  gemm_core(inter, NK2, t0, W2t, NK2, h0, NK2 / 64, lds, acc);

  const int tid = threadIdx.x, lane = tid & 63, wave = tid >> 6;
  const int wr = wave >> 1, wc = wave & 1, fr = lane & 15, fq = lane >> 4;
  const int rowBase = t0 + wr * 64 + fq * 4;
#pragma unroll
  for (int i = 0; i < 4; ++i)
#pragma unroll
    for (int j = 0; j < 4; ++j)
#pragma unroll
      for (int r = 0; r < 4; ++r)
        out[(size_t)(rowBase + i * 16 + r) * NH + h0 + wc * 64 + j * 16 + fr] =
            acc[i][j][r];
}

extern "C" void kernel_launch(void* const* d_in, const int* in_sizes, int n_in,
                              void* d_out, int out_size, void* d_ws, size_t ws_size,
                              hipStream_t stream) {
  const float* x = (const float*)d_in[0];    // [NT][NH]
  const float* rw = (const float*)d_in[1];   // [NT][NE]
  // d_in[2] router_indices: unused by reference (dense all-experts)
  const float* w1 = (const float*)d_in[3];   // [NE][NH][2*NI]
  const float* w2 = (const float*)d_in[4];   // [NE][NI][NH]
  float* out = (float*)d_out;

  char* ws = (char*)d_ws;
  // ws layout (bf16): Xb 16MB | W1t 48MB | W2t 24MB | inter 48MB  = 136 MiB
  unsigned short* Xb = (unsigned short*)ws;                               // [NT][NH]
  unsigned short* W1t = (unsigned short*)(ws + 16777216);                 // [NE][1536perm][NH]
  unsigned short* W2t = (unsigned short*)(ws + 16777216 + 50331648);      // [NH][NK2]
  unsigned short* inter = (unsigned short*)(ws + 16777216 + 50331648 + 25165824); // [NT][NK2]

  // 1) convert x
  k_cvt<<<dim3((NT * NH) / (256 * 8)), dim3(256), 0, stream>>>(x, Xb, (long)NT * NH);
  // 2) W1 [E][H][2I] -> W1t [E][perm(2I)][H], gate/up 16-interleaved
  k_transpose_cvt<<<dim3((2 * NI) / 32, NH / 32, NE), dim3(32, 8), 0, stream>>>(
      w1, W1t, NH, 2 * NI, (long)NH * 2 * NI, (long)2 * NI * NH, NH, 1);
  // 3) W2 [E][I][H] -> W2t [H][E*I]
  k_transpose_cvt<<<dim3(NH / 32, NI / 32, NE), dim3(32, 8), 0, stream>>>(
      w2, W2t, NI, NH, (long)NI * NH, (long)NI, NK2, 0);
  // 4) GEMM1 fused silu/up/rw -> inter
  k_gemm1<<<dim3((2 * NI) / 128, NT / 256, NE), dim3(512), 0, stream>>>(Xb, W1t, rw, inter);
  // 5) GEMM2 -> out
  k_gemm2<<<dim3(NH / 128, NT / 256), dim3(512), 0, stream>>>(inter, W2t, out);
}

// Round 3
// 372.215 us; speedup vs baseline: 1.2731x; 1.0156x over previous
//
#include <hip/hip_runtime.h>
#include <cstdint>
#include <cstddef>

// Problem constants (Qwen3VLMoeTextExperts): E=8, H=2048, I=768, T=B*S=4096
#define NE 8
#define NH 2048
#define NI 768
#define NT 4096
#define NK2 6144   // NE*NI : K of second GEMM

typedef __bf16 bf16x8 __attribute__((ext_vector_type(8)));
typedef float f32x4 __attribute__((ext_vector_type(4)));
typedef unsigned short u16x8 __attribute__((ext_vector_type(8)));

__device__ __forceinline__ unsigned short f2bf(float f) {
  unsigned int u = __builtin_bit_cast(unsigned int, f);
  u += 0x7fffu + ((u >> 16) & 1u);   // round-to-nearest-even
  return (unsigned short)(u >> 16);
}

// async global->LDS, 16B per lane (dest must be linear: base + lane*16).
__device__ __forceinline__ void gload_lds16(const void* g, void* s) {
  __builtin_amdgcn_global_load_lds(
      (const __attribute__((address_space(1))) unsigned int*)g,
      (__attribute__((address_space(3))) unsigned int*)s, 16, 0, 0);
}

// ---------------- convert f32 -> bf16 (vectorized x8) ----------------
__global__ __launch_bounds__(256) void k_cvt(const float* __restrict__ in,
                                             unsigned short* __restrict__ out,
                                             long n) {
  long i = ((long)blockIdx.x * blockDim.x + threadIdx.x) * 8;
  if (i >= n) return;
  float4 f0 = *reinterpret_cast<const float4*>(in + i);
  float4 f1 = *reinterpret_cast<const float4*>(in + i + 4);
  u16x8 o;
  o[0] = f2bf(f0.x); o[1] = f2bf(f0.y); o[2] = f2bf(f0.z); o[3] = f2bf(f0.w);
  o[4] = f2bf(f1.x); o[5] = f2bf(f1.y); o[6] = f2bf(f1.z); o[7] = f2bf(f1.w);
  *reinterpret_cast<u16x8*>(out + i) = o;
}

// ------------- transpose + convert: out[b*oBS + perm(c)*oCS + r] = in[b][r][c] -------------
// mode 0: perm = identity. mode 1 (gate_up): interleave gate/up at 16-col
// granularity: gate col c -> (c>>4)*32 + (c&15); up col c -> (c>>4)*32 + 16 + (c&15).
__global__ __launch_bounds__(256) void k_transpose_cvt(
    const float* __restrict__ in, unsigned short* __restrict__ out,
    int R, int C, long inBS, long outBS, int outCS, int mode) {
  __shared__ float tile[32][33];
  const int b = blockIdx.z;
  const int r0 = blockIdx.y * 32, c0 = blockIdx.x * 32;
  const int tx = threadIdx.x, ty = threadIdx.y;
  const float* ib = in + (long)b * inBS;
#pragma unroll
  for (int d = 0; d < 4; d++)
    tile[ty + d * 8][tx] = ib[(long)(r0 + ty + d * 8) * C + c0 + tx];
  __syncthreads();
#pragma unroll
  for (int d = 0; d < 4; d++) {
    int c = c0 + ty + d * 8;   // original out-major index
    int r = r0 + tx;           // out minor index (coalesced)
    int orow;
    if (mode == 1) {
      int z = (c >= NI) ? 1 : 0;
      int cc = c - z * NI;
      orow = ((cc >> 4) << 5) + (z << 4) + (cc & 15);
    } else {
      orow = c;
    }
    out[(long)b * outBS + (long)orow * outCS + r] = f2bf(tile[tx][ty + d * 8]);
  }
}

// ==================== GEMM1: 8-phase deep-pipelined 256x256 ====================
// BM=256 A-rows (tokens), BNR=256 B-rows (=128 inter cols), BK=64.
// 8 waves: wr=wave>>2 (M), wc=wave&3 (N). Per-wave output rows are
// M-interleaved: rA(i) = (i>>2)*128 + wr*64 + (i&3)*16 + fr  -> quadrant iL
// reads A rows [0,128) ("A half0"), iH reads [128,256).  Similarly
// rB(j) = (j>>1)*128 + wc*32 + (j&1)*16 + fr -> jL reads B half0, jH half1.
// Two K-tile LDS buffers (buf0=even tiles, buf1=odd). Per phase: 12
// ds_read_b128 + 1 half-tile prefetch (2 gload_lds) + 2 barriers + 16 MFMA.
// Issue slots derived from region-death; vmcnt(4) at phases 4 and 8 closes
// the schedule race-free (each half lands >=2 phases before first read).
// Swizzle: chunk c of row r stored at c^(r&7); read side keys on fr&7
// (rA&7==fr&7 since all other terms are multiples of 16). 0 bank conflicts.

__global__ __launch_bounds__(512, 2) void k_gemm1(
    const unsigned short* __restrict__ Xb,    // [NT][NH] bf16
    const unsigned short* __restrict__ W1t,   // [NE][1536(perm)][NH] bf16
    const float* __restrict__ rw,             // [NT][NE]
    unsigned short* __restrict__ inter) {     // [NT][NK2] bf16
  __shared__ unsigned short lds[2][2][16384];   // [buf][A/B][256*64] = 128 KiB

  const int e = blockIdx.z;
  const int t0 = blockIdx.y * 256;
  const int bn = blockIdx.x;                 // B-rows [bn*256, +256)
  const int tid = threadIdx.x;
  const int lane = tid & 63;
  const int wave = tid >> 6;
  const int wr = wave >> 2, wc = wave & 3;
  const int fr = lane & 15, fq = lane >> 4;

  const unsigned short* Ag = Xb;             // ldA = NH
  const unsigned short* Bg = W1t + (size_t)e * (2 * NI) * NH;  // ldB = NH
  const int rowA0 = t0, rowB0 = bn * 256;
  const int nkt = NH / 64;                   // 32
  const int NIT = nkt / 2;                   // 16

  // --- staging source pointers (swizzled source, linear LDS dest) ---
  const int cl0 = tid, cl1 = 512 + tid;
  const int rih0 = cl0 >> 3, ck0 = cl0 & 7;
  const int rih1 = cl1 >> 3, ck1 = cl1 & 7;
  const unsigned short* sA0q0 = Ag + (size_t)(rowA0 + rih0) * NH + ((ck0 ^ (rih0 & 7)) << 3);
  const unsigned short* sA0q1 = Ag + (size_t)(rowA0 + rih1) * NH + ((ck1 ^ (rih1 & 7)) << 3);
  const unsigned short* sA1q0 = Ag + (size_t)(rowA0 + 128 + rih0) * NH + ((ck0 ^ (rih0 & 7)) << 3);
  const unsigned short* sA1q1 = Ag + (size_t)(rowA0 + 128 + rih1) * NH + ((ck1 ^ (rih1 & 7)) << 3);
  const unsigned short* sB0q0 = Bg + (size_t)(rowB0 + rih0) * NH + ((ck0 ^ (rih0 & 7)) << 3);
  const unsigned short* sB0q1 = Bg + (size_t)(rowB0 + rih1) * NH + ((ck1 ^ (rih1 & 7)) << 3);
  const unsigned short* sB1q0 = Bg + (size_t)(rowB0 + 128 + rih0) * NH + ((ck0 ^ (rih0 & 7)) << 3);
  const unsigned short* sB1q1 = Bg + (size_t)(rowB0 + 128 + rih1) * NH + ((ck1 ^ (rih1 & 7)) << 3);
  const int d0 = cl0 * 8, d1 = cl1 * 8;

#define STG_A(BUFI, H, KT) do { \
    gload_lds16(sA##H##q0 + (size_t)(KT) * 64, &lds[BUFI][0][(H) * 8192 + d0]); \
    gload_lds16(sA##H##q1 + (size_t)(KT) * 64, &lds[BUFI][0][(H) * 8192 + d1]); \
  } while (0)
#define STG_B(BUFI, H, KT) do { \
    gload_lds16(sB##H##q0 + (size_t)(KT) * 64, &lds[BUFI][1][(H) * 8192 + d0]); \
    gload_lds16(sB##H##q1 + (size_t)(KT) * 64, &lds[BUFI][1][(H) * 8192 + d1]); \
  } while (0)

  f32x4 acc[8][4];
#pragma unroll
  for (int i = 0; i < 8; ++i)
#pragma unroll
    for (int j = 0; j < 4; ++j) acc[i][j] = (f32x4){0.f, 0.f, 0.f, 0.f};

  const int swz = fr & 7;   // read-side swizzle key (== rA&7 == rB&7)

#define PHASE(BUFI, IH, JH, ISSUE, DOWAIT) do { \
    bf16x8 af[4][2], bf[2][2]; \
    _Pragma("unroll") \
    for (int ii = 0; ii < 4; ++ii) { \
      const int rA = (IH) * 128 + wr * 64 + ii * 16 + fr; \
      _Pragma("unroll") \
      for (int kk = 0; kk < 2; ++kk) \
        af[ii][kk] = *reinterpret_cast<const bf16x8*>( \
            &lds[BUFI][0][rA * 64 + (((kk * 4 + fq) ^ swz) << 3)]); \
    } \
    _Pragma("unroll") \
    for (int jj = 0; jj < 2; ++jj) { \
      const int rB = (JH) * 128 + wc * 32 + jj * 16 + fr; \
      _Pragma("unroll") \
      for (int kk = 0; kk < 2; ++kk) \
        bf[jj][kk] = *reinterpret_cast<const bf16x8*>( \
            &lds[BUFI][1][rB * 64 + (((kk * 4 + fq) ^ swz) << 3)]); \
    } \
    ISSUE; \
    if (DOWAIT) asm volatile("s_waitcnt vmcnt(4)" ::: "memory"); \
    __builtin_amdgcn_sched_barrier(0); \
    __builtin_amdgcn_s_barrier(); \
    __builtin_amdgcn_sched_barrier(0); \
    __builtin_amdgcn_s_setprio(1); \
    _Pragma("unroll") \
    for (int kk = 0; kk < 2; ++kk) \
      _Pragma("unroll") \
      for (int ii = 0; ii < 4; ++ii) \
        _Pragma("unroll") \
        for (int jj = 0; jj < 2; ++jj) \
          acc[(IH) * 4 + ii][(JH) * 2 + jj] = __builtin_amdgcn_mfma_f32_16x16x32_bf16( \
              af[ii][kk], bf[jj][kk], acc[(IH) * 4 + ii][(JH) * 2 + jj], 0, 0, 0); \
    __builtin_amdgcn_s_setprio(0); \
    __builtin_amdgcn_sched_barrier(0); \
    __builtin_amdgcn_s_barrier(); \
    __builtin_amdgcn_sched_barrier(0); \
  } while (0)

  // prologue: T0 all 4 halves, then T1-{Bh0, Ah0}; wait T0 landed.
  STG_B(0, 0, 0); STG_A(0, 0, 0); STG_A(0, 1, 0); STG_B(0, 1, 0);
  STG_B(1, 0, 1); STG_A(1, 0, 1);
  asm volatile("s_waitcnt vmcnt(4)" ::: "memory");
  __builtin_amdgcn_sched_barrier(0);
  __builtin_amdgcn_s_barrier();
  __builtin_amdgcn_sched_barrier(0);

  for (int it = 0; it < NIT; ++it) {
    const int kt1 = 2 * it + 1;
    const int p0 = (2 * it + 2 < nkt) ? 2 * it + 2 : nkt - 1;   // clamped (never OOB)
    const int p1 = (2 * it + 3 < nkt) ? 2 * it + 3 : nkt - 1;
    PHASE(0, 0, 0, STG_A(1, 1, kt1), 0);   // buf0 (iL,jL); finish buf1 tile: A-h1
    PHASE(0, 1, 0, STG_B(1, 1, kt1), 0);   // buf0 (iH,jL); finish buf1 tile: B-h1
    PHASE(0, 0, 1, STG_B(0, 0, p0), 0);    // buf0 (iL,jH); next buf0: B-h0
    PHASE(0, 1, 1, STG_A(0, 0, p0), 1);    // buf0 (iH,jH); next buf0: A-h0; vmcnt(4)
    PHASE(1, 0, 0, STG_A(0, 1, p0), 0);    // buf1 (iL,jL); next buf0: A-h1
    PHASE(1, 1, 0, STG_B(0, 1, p0), 0);    // buf1 (iH,jL); next buf0: B-h1
    PHASE(1, 0, 1, STG_B(1, 0, p1), 0);    // buf1 (iL,jH); next buf1: B-h0
    PHASE(1, 1, 1, STG_A(1, 0, p1), 1);    // buf1 (iH,jH); next buf1: A-h0; vmcnt(4)
  }
  asm volatile("s_waitcnt vmcnt(0)" ::: "memory");

#undef PHASE
#undef STG_A
#undef STG_B

  // epilogue: silu(gate)*up*rw -> bf16.  acc[i][2p]=gate, acc[i][2p+1]=up for
  // inter col (within expert) = (p*4 + wc)*16 + fr; token row from rA(i).
#pragma unroll
  for (int i = 0; i < 8; ++i) {
    const int trow = t0 + (i >> 2) * 128 + wr * 64 + (i & 3) * 16 + fq * 4;
#pragma unroll
    for (int r = 0; r < 4; ++r) {
      const int t = trow + r;
      const float rwv = rw[(size_t)t * NE + e];
#pragma unroll
      for (int p = 0; p < 2; ++p) {
        float g = acc[i][2 * p][r];
        float u = acc[i][2 * p + 1][r];
        float s = g / (1.f + __expf(-g));  // silu
        const int col = bn * 128 + (p * 4 + wc) * 16 + fr;
        inter[(size_t)t * NK2 + e * NI + col] = f2bf(rwv * u * s);
      }
    }
  }
}

// ==================== GEMM2 (unchanged R2 structure) ====================
// BM=256, BNB=128, BK=64, 3-buffer counted-vmcnt pipeline.
#define BUF_US 24576   // ushorts per buffer (48 KiB)
#define B_OFF 16384    // B region offset within buffer (ushorts)

__device__ __forceinline__ void gemm_core(
    const unsigned short* __restrict__ A, int ldA, int rowA0,
    const unsigned short* __restrict__ B, int ldB, int rowB0,
    int nkt, unsigned short* lds, f32x4 acc[4][4]) {
  const int tid = threadIdx.x;
  const int lane = tid & 63;
  const int wave = tid >> 6;
  const int wr = wave >> 1;        // 0..3 (M)
  const int wc = wave & 1;         // 0..1 (N)
  const int fr = lane & 15, fq = lane >> 4;

  size_t sA[4]; int dA[4];
#pragma unroll
  for (int q = 0; q < 4; ++q) {
    int chunk = q * 512 + tid;
    int row = chunk >> 3, c = chunk & 7;
    sA[q] = (size_t)(rowA0 + row) * ldA + ((c ^ (row & 7)) << 3);
    dA[q] = chunk * 8;
  }
  size_t sB[2]; int dB[2];
#pragma unroll
  for (int q = 0; q < 2; ++q) {
    int chunk = q * 512 + tid;
    int row = chunk >> 3, c = chunk & 7;
    sB[q] = (size_t)(rowB0 + row) * ldB + ((c ^ (row & 7)) << 3);
    dB[q] = B_OFF + chunk * 8;
  }

  int aO[2][4], bO[2][4];
#pragma unroll
  for (int kk = 0; kk < 2; ++kk) {
#pragma unroll
    for (int i = 0; i < 4; ++i) {
      int rowA = wr * 64 + i * 16 + fr;
      aO[kk][i] = rowA * 64 + (((kk * 4 + fq) ^ (rowA & 7)) << 3);
      int rowB = wc * 64 + i * 16 + fr;
      bO[kk][i] = B_OFF + rowB * 64 + (((kk * 4 + fq) ^ (rowB & 7)) << 3);
    }
  }

#pragma unroll
  for (int i = 0; i < 4; ++i)
#pragma unroll
    for (int j = 0; j < 4; ++j) acc[i][j] = (f32x4){0.f, 0.f, 0.f, 0.f};

#pragma unroll
  for (int q = 0; q < 4; ++q) gload_lds16(A + sA[q], lds + dA[q]);
#pragma unroll
  for (int q = 0; q < 2; ++q) gload_lds16(B + sB[q], lds + dB[q]);
#pragma unroll
  for (int q = 0; q < 4; ++q) gload_lds16(A + sA[q] + 64, lds + BUF_US + dA[q]);
#pragma unroll
  for (int q = 0; q < 2; ++q) gload_lds16(B + sB[q] + 64, lds + BUF_US + dB[q]);

  int bi = 0, bs = 2;
  for (int kt = 0; kt < nkt; ++kt) {
    if (kt == nkt - 1) {
      asm volatile("s_waitcnt vmcnt(0)" ::: "memory");
    } else {
      asm volatile("s_waitcnt vmcnt(6)" ::: "memory");
    }
    __builtin_amdgcn_s_barrier();
    __builtin_amdgcn_sched_barrier(0);

    if (kt + 2 < nkt) {
      const int k0 = (kt + 2) * 64;
      unsigned short* tb = lds + bs * BUF_US;
#pragma unroll
      for (int q = 0; q < 4; ++q) gload_lds16(A + sA[q] + k0, tb + dA[q]);
#pragma unroll
      for (int q = 0; q < 2; ++q) gload_lds16(B + sB[q] + k0, tb + dB[q]);
    }

    const unsigned short* cb = lds + bi * BUF_US;
#pragma unroll
    for (int kk = 0; kk < 2; ++kk) {
      bf16x8 a[4], b[4];
#pragma unroll
      for (int i = 0; i < 4; ++i) a[i] = *reinterpret_cast<const bf16x8*>(cb + aO[kk][i]);
#pragma unroll
      for (int j = 0; j < 4; ++j) b[j] = *reinterpret_cast<const bf16x8*>(cb + bO[kk][j]);
      __builtin_amdgcn_s_setprio(1);
#pragma unroll
      for (int i = 0; i < 4; ++i)
#pragma unroll
        for (int j = 0; j < 4; ++j)
          acc[i][j] = __builtin_amdgcn_mfma_f32_16x16x32_bf16(a[i], b[j], acc[i][j], 0, 0, 0);
      __builtin_amdgcn_s_setprio(0);
    }

    bi = (bi == 2) ? 0 : bi + 1;
    bs = (bs == 2) ? 0 : bs + 1;
  }
}

__global__ __launch_bounds__(512, 2) void k_gemm2(
    const unsigned short* __restrict__ inter,  // [NT][NK2] bf16
    const unsigned short* __restrict__ W2t,    // [NH][NK2] bf16
    float* __restrict__ out) {                 // [NT][NH] f32
  __shared__ unsigned short lds[3 * BUF_US];
  const int t0 = blockIdx.y * 256;
  const int h0 = blockIdx.x * 128;
  f32x4 acc[4][4];
  gemm_core(inter, NK2, t0, W2t, NK2, h0, NK2 / 64, lds, acc);

  const int tid = threadIdx.x, lane = tid & 63, wave = tid >> 6;
  const int wr = wave >> 1, wc = wave & 1, fr = lane & 15, fq = lane >> 4;
  const int rowBase = t0 + wr * 64 + fq * 4;
#pragma unroll
  for (int i = 0; i < 4; ++i)
#pragma unroll
    for (int j = 0; j < 4; ++j)
#pragma unroll
      for (int r = 0; r < 4; ++r)
        out[(size_t)(rowBase + i * 16 + r) * NH + h0 + wc * 64 + j * 16 + fr] =
            acc[i][j][r];
}

extern "C" void kernel_launch(void* const* d_in, const int* in_sizes, int n_in,
                              void* d_out, int out_size, void* d_ws, size_t ws_size,
                              hipStream_t stream) {
  const float* x = (const float*)d_in[0];    // [NT][NH]
  const float* rw = (const float*)d_in[1];   // [NT][NE]
  // d_in[2] router_indices: unused by reference (dense all-experts)
  const float* w1 = (const float*)d_in[3];   // [NE][NH][2*NI]
  const float* w2 = (const float*)d_in[4];   // [NE][NI][NH]
  float* out = (float*)d_out;

  char* ws = (char*)d_ws;
  // ws layout (bf16): Xb 16MB | W1t 48MB | W2t 24MB | inter 48MB  = 136 MiB
  unsigned short* Xb = (unsigned short*)ws;                               // [NT][NH]
  unsigned short* W1t = (unsigned short*)(ws + 16777216);                 // [NE][1536perm][NH]
  unsigned short* W2t = (unsigned short*)(ws + 16777216 + 50331648);      // [NH][NK2]
  unsigned short* inter = (unsigned short*)(ws + 16777216 + 50331648 + 25165824); // [NT][NK2]

  // 1) convert x
  k_cvt<<<dim3((NT * NH) / (256 * 8)), dim3(256), 0, stream>>>(x, Xb, (long)NT * NH);
  // 2) W1 [E][H][2I] -> W1t [E][perm(2I)][H], gate/up 16-interleaved
  k_transpose_cvt<<<dim3((2 * NI) / 32, NH / 32, NE), dim3(32, 8), 0, stream>>>(
      w1, W1t, NH, 2 * NI, (long)NH * 2 * NI, (long)2 * NI * NH, NH, 1);
  // 3) W2 [E][I][H] -> W2t [H][E*I]
  k_transpose_cvt<<<dim3(NH / 32, NI / 32, NE), dim3(32, 8), 0, stream>>>(
      w2, W2t, NI, NH, (long)NI * NH, (long)NI, NK2, 0);
  // 4) GEMM1 fused silu/up/rw -> inter (8-phase, 256x256)
  k_gemm1<<<dim3((2 * NI) / 256, NT / 256, NE), dim3(512), 0, stream>>>(Xb, W1t, rw, inter);
  // 5) GEMM2 -> out
  k_gemm2<<<dim3(NH / 128, NT / 256), dim3(512), 0, stream>>>(inter, W2t, out);
}

// Round 4
// 349.824 us; speedup vs baseline: 1.3546x; 1.0640x over previous
//
#include <hip/hip_runtime.h>
#include <cstdint>
#include <cstddef>

// Problem constants (Qwen3VLMoeTextExperts): E=8, H=2048, I=768, T=B*S=4096
#define NE 8
#define NH 2048
#define NI 768
#define NT 4096
#define NK2 6144   // NE*NI : K of second GEMM

typedef __bf16 bf16x8 __attribute__((ext_vector_type(8)));
typedef float f32x4 __attribute__((ext_vector_type(4)));
typedef unsigned short u16x8 __attribute__((ext_vector_type(8)));

__device__ __forceinline__ unsigned short f2bf(float f) {
  unsigned int u = __builtin_bit_cast(unsigned int, f);
  u += 0x7fffu + ((u >> 16) & 1u);   // round-to-nearest-even
  return (unsigned short)(u >> 16);
}

// async global->LDS, 16B per lane (dest must be linear: base + lane*16).
__device__ __forceinline__ void gload_lds16(const void* g, void* s) {
  __builtin_amdgcn_global_load_lds(
      (const __attribute__((address_space(1))) unsigned int*)g,
      (__attribute__((address_space(3))) unsigned int*)s, 16, 0, 0);
}

// ---------------- convert f32 -> bf16 (vectorized x8) ----------------
__global__ __launch_bounds__(256) void k_cvt(const float* __restrict__ in,
                                             unsigned short* __restrict__ out,
                                             long n) {
  long i = ((long)blockIdx.x * blockDim.x + threadIdx.x) * 8;
  if (i >= n) return;
  float4 f0 = *reinterpret_cast<const float4*>(in + i);
  float4 f1 = *reinterpret_cast<const float4*>(in + i + 4);
  u16x8 o;
  o[0] = f2bf(f0.x); o[1] = f2bf(f0.y); o[2] = f2bf(f0.z); o[3] = f2bf(f0.w);
  o[4] = f2bf(f1.x); o[5] = f2bf(f1.y); o[6] = f2bf(f1.z); o[7] = f2bf(f1.w);
  *reinterpret_cast<u16x8*>(out + i) = o;
}

// ------------- transpose + convert: out[b*oBS + perm(c)*oCS + r] = in[b][r][c] -------------
// mode 0: perm = identity. mode 1 (gate_up): interleave gate/up at 16-col
// granularity: gate col c -> (c>>4)*32 + (c&15); up col c -> (c>>4)*32 + 16 + (c&15).
__global__ __launch_bounds__(256) void k_transpose_cvt(
    const float* __restrict__ in, unsigned short* __restrict__ out,
    int R, int C, long inBS, long outBS, int outCS, int mode) {
  __shared__ float tile[32][33];
  const int b = blockIdx.z;
  const int r0 = blockIdx.y * 32, c0 = blockIdx.x * 32;
  const int tx = threadIdx.x, ty = threadIdx.y;
  const float* ib = in + (long)b * inBS;
#pragma unroll
  for (int d = 0; d < 4; d++)
    tile[ty + d * 8][tx] = ib[(long)(r0 + ty + d * 8) * C + c0 + tx];
  __syncthreads();
#pragma unroll
  for (int d = 0; d < 4; d++) {
    int c = c0 + ty + d * 8;   // original out-major index
    int r = r0 + tx;           // out minor index (coalesced)
    int orow;
    if (mode == 1) {
      int z = (c >= NI) ? 1 : 0;
      int cc = c - z * NI;
      orow = ((cc >> 4) << 5) + (z << 4) + (cc & 15);
    } else {
      orow = c;
    }
    out[(long)b * outBS + (long)orow * outCS + r] = f2bf(tile[tx][ty + d * 8]);
  }
}

// ==================== GEMM1: 8-phase, ONE barrier/phase, 256x256 ====================
// BM=256 tokens, 256 B-rows (=128 inter cols), BK=64. 8 waves: wr=wave>>2 (M),
// wc=wave&3 (N); per-wave output 128x64 (M-interleaved halves).
// Phase (buf, IH, JH): reads A-half IH (8 ds_read_b128), B-half JH (4 reads,
// REUSED by the following IH=1 phase), issues 1 half-tile stage (2 gload_lds),
// [vmcnt(4) at ph4/ph8], ONE barrier, 16 MFMA.
// One barrier per phase is sufficient: all of phase p's ds_reads precede its
// barrier, so any staging issued in phase p+1 targets regions all waves
// finished reading (region-death ledger below). vmcnt-before-barrier makes
// staging completion collective before dependent reads.
//
// Reads:  ph1(b0,A0,B0) ph2(b0,A1,B0) ph3(b0,A0,B1) ph4(b0,A1,B1)
//         ph5(b1,A0,B0) ph6(b1,A1,B0) ph7(b1,A0,B1) ph8(b1,A1,B1)
// Deaths: b0: B0@ph2 A0@ph3 A1,B1@ph4 | b1: B0@ph6 A0@ph7 A1,B1@ph8
// Issue:  ph1:B1(2i+1) ph2:A1(2i+1) ph3:B0(2i+2) ph4:A0(2i+2)+vmcnt(4)
//         ph5:B1(2i+2) ph6:A1(2i+2) ph7:B0(2i+3) ph8:A0(2i+3)+vmcnt(4)
//   every slot > its region's death phase; every vmcnt(4) leaves exactly the
//   last 2 halves in flight, so required halves have 2-5 phases of cover.

__global__ __launch_bounds__(512, 2) void k_gemm1(
    const unsigned short* __restrict__ Xb,    // [NT][NH] bf16
    const unsigned short* __restrict__ W1t,   // [NE][1536(perm)][NH] bf16
    const float* __restrict__ rw,             // [NT][NE]
    unsigned short* __restrict__ inter) {     // [NT][NK2] bf16
  __shared__ unsigned short lds[2][2][16384];   // [buf][A/B][half*8192+...] 128 KiB

  const int e = blockIdx.z;
  const int t0 = blockIdx.y * 256;
  const int bn = blockIdx.x;                 // B-rows [bn*256, +256)
  const int tid = threadIdx.x;
  const int lane = tid & 63;
  const int wave = tid >> 6;
  const int wr = wave >> 2, wc = wave & 3;
  const int fr = lane & 15, fq = lane >> 4;

  const unsigned short* Ag = Xb;             // ldA = NH
  const unsigned short* Bg = W1t + (size_t)e * (2 * NI) * NH;  // ldB = NH
  const int rowA0 = t0, rowB0 = bn * 256;
  const int nkt = NH / 64;                   // 32
  const int NIT = nkt / 2;                   // 16

  // --- staging source pointers (swizzled source, linear LDS dest) ---
  const int cl0 = tid, cl1 = 512 + tid;
  const int rih0 = cl0 >> 3, ck0 = cl0 & 7;
  const int rih1 = cl1 >> 3, ck1 = cl1 & 7;
  const unsigned short* sA0q0 = Ag + (size_t)(rowA0 + rih0) * NH + ((ck0 ^ (rih0 & 7)) << 3);
  const unsigned short* sA0q1 = Ag + (size_t)(rowA0 + rih1) * NH + ((ck1 ^ (rih1 & 7)) << 3);
  const unsigned short* sA1q0 = Ag + (size_t)(rowA0 + 128 + rih0) * NH + ((ck0 ^ (rih0 & 7)) << 3);
  const unsigned short* sA1q1 = Ag + (size_t)(rowA0 + 128 + rih1) * NH + ((ck1 ^ (rih1 & 7)) << 3);
  const unsigned short* sB0q0 = Bg + (size_t)(rowB0 + rih0) * NH + ((ck0 ^ (rih0 & 7)) << 3);
  const unsigned short* sB0q1 = Bg + (size_t)(rowB0 + rih1) * NH + ((ck1 ^ (rih1 & 7)) << 3);
  const unsigned short* sB1q0 = Bg + (size_t)(rowB0 + 128 + rih0) * NH + ((ck0 ^ (rih0 & 7)) << 3);
  const unsigned short* sB1q1 = Bg + (size_t)(rowB0 + 128 + rih1) * NH + ((ck1 ^ (rih1 & 7)) << 3);
  const int d0 = cl0 * 8, d1 = cl1 * 8;

#define STG_A(BUFI, H, KT) do { \
    gload_lds16(sA##H##q0 + (size_t)(KT) * 64, &lds[BUFI][0][(H) * 8192 + d0]); \
    gload_lds16(sA##H##q1 + (size_t)(KT) * 64, &lds[BUFI][0][(H) * 8192 + d1]); \
  } while (0)
#define STG_B(BUFI, H, KT) do { \
    gload_lds16(sB##H##q0 + (size_t)(KT) * 64, &lds[BUFI][1][(H) * 8192 + d0]); \
    gload_lds16(sB##H##q1 + (size_t)(KT) * 64, &lds[BUFI][1][(H) * 8192 + d1]); \
  } while (0)

  f32x4 acc[8][4];
#pragma unroll
  for (int i = 0; i < 8; ++i)
#pragma unroll
    for (int j = 0; j < 4; ++j) acc[i][j] = (f32x4){0.f, 0.f, 0.f, 0.f};

  const int swz = fr & 7;   // read-side swizzle key (== row&7 for all frag rows)
  bf16x8 bfr[2][2];         // B fragments, persisted across the IH=0 -> IH=1 pair

#define PHASE(BUFI, IH, JH, RDB, ISSUE, DOWAIT) do { \
    if (RDB) { \
      _Pragma("unroll") \
      for (int jj = 0; jj < 2; ++jj) { \
        const int rB = (JH) * 128 + wc * 32 + jj * 16 + fr; \
        _Pragma("unroll") \
        for (int kk = 0; kk < 2; ++kk) \
          bfr[jj][kk] = *reinterpret_cast<const bf16x8*>( \
              &lds[BUFI][1][rB * 64 + (((kk * 4 + fq) ^ swz) << 3)]); \
      } \
    } \
    bf16x8 af[4][2]; \
    _Pragma("unroll") \
    for (int ii = 0; ii < 4; ++ii) { \
      const int rA = (IH) * 128 + wr * 64 + ii * 16 + fr; \
      _Pragma("unroll") \
      for (int kk = 0; kk < 2; ++kk) \
        af[ii][kk] = *reinterpret_cast<const bf16x8*>( \
            &lds[BUFI][0][rA * 64 + (((kk * 4 + fq) ^ swz) << 3)]); \
    } \
    ISSUE; \
    if (DOWAIT) asm volatile("s_waitcnt vmcnt(4)" ::: "memory"); \
    __builtin_amdgcn_sched_barrier(0); \
    __builtin_amdgcn_s_barrier(); \
    __builtin_amdgcn_sched_barrier(0); \
    __builtin_amdgcn_s_setprio(1); \
    _Pragma("unroll") \
    for (int kk = 0; kk < 2; ++kk) \
      _Pragma("unroll") \
      for (int ii = 0; ii < 4; ++ii) \
        _Pragma("unroll") \
        for (int jj = 0; jj < 2; ++jj) \
          acc[(IH) * 4 + ii][(JH) * 2 + jj] = __builtin_amdgcn_mfma_f32_16x16x32_bf16( \
              af[ii][kk], bfr[jj][kk], acc[(IH) * 4 + ii][(JH) * 2 + jj], 0, 0, 0); \
    __builtin_amdgcn_s_setprio(0); \
    __builtin_amdgcn_sched_barrier(0); \
  } while (0)

  // prologue: tile0 all 4 halves -> buf0; tile1 {B0,A0} -> buf1; T0 landed.
  STG_B(0, 0, 0); STG_A(0, 0, 0); STG_A(0, 1, 0); STG_B(0, 1, 0);
  STG_B(1, 0, 1); STG_A(1, 0, 1);
  asm volatile("s_waitcnt vmcnt(4)" ::: "memory");
  __builtin_amdgcn_sched_barrier(0);
  __builtin_amdgcn_s_barrier();
  __builtin_amdgcn_sched_barrier(0);

  for (int it = 0; it < NIT; ++it) {
    const int kt1 = 2 * it + 1;
    const int kt2 = (2 * it + 2 < nkt) ? 2 * it + 2 : nkt - 1;  // clamped: re-stage
    const int kt3 = (2 * it + 3 < nkt) ? 2 * it + 3 : nkt - 1;  // into dead regions
    PHASE(0, 0, 0, 1, STG_B(1, 1, kt1), 0);
    PHASE(0, 1, 0, 0, STG_A(1, 1, kt1), 0);
    PHASE(0, 0, 1, 1, STG_B(0, 0, kt2), 0);
    PHASE(0, 1, 1, 0, STG_A(0, 0, kt2), 1);
    PHASE(1, 0, 0, 1, STG_B(0, 1, kt2), 0);
    PHASE(1, 1, 0, 0, STG_A(0, 1, kt2), 0);
    PHASE(1, 0, 1, 1, STG_B(1, 0, kt3), 0);
    PHASE(1, 1, 1, 0, STG_A(1, 0, kt3), 1);
  }
  asm volatile("s_waitcnt vmcnt(0)" ::: "memory");

#undef PHASE
#undef STG_A
#undef STG_B

  // epilogue: silu(gate)*up*rw -> bf16.  acc[i][2p]=gate, acc[i][2p+1]=up for
  // inter col (within expert) = (p*4 + wc)*16 + fr; token row from rA(i).
#pragma unroll
  for (int i = 0; i < 8; ++i) {
    const int trow = t0 + (i >> 2) * 128 + wr * 64 + (i & 3) * 16 + fq * 4;
#pragma unroll
    for (int r = 0; r < 4; ++r) {
      const int t = trow + r;
      const float rwv = rw[(size_t)t * NE + e];
#pragma unroll
      for (int p = 0; p < 2; ++p) {
        float g = acc[i][2 * p][r];
        float u = acc[i][2 * p + 1][r];
        float s = g / (1.f + __expf(-g));  // silu
        const int col = bn * 128 + (p * 4 + wc) * 16 + fr;
        inter[(size_t)t * NK2 + e * NI + col] = f2bf(rwv * u * s);
      }
    }
  }
}

// ==================== GEMM2 (unchanged R2 structure) ====================
// BM=256, BNB=128, BK=64, 3-buffer counted-vmcnt pipeline.
#define BUF_US 24576   // ushorts per buffer (48 KiB)
#define B_OFF 16384    // B region offset within buffer (ushorts)

__device__ __forceinline__ void gemm_core(
    const unsigned short* __restrict__ A, int ldA, int rowA0,
    const unsigned short* __restrict__ B, int ldB, int rowB0,
    int nkt, unsigned short* lds, f32x4 acc[4][4]) {
  const int tid = threadIdx.x;
  const int lane = tid & 63;
  const int wave = tid >> 6;
  const int wr = wave >> 1;        // 0..3 (M)
  const int wc = wave & 1;         // 0..1 (N)
  const int fr = lane & 15, fq = lane >> 4;

  size_t sA[4]; int dA[4];
#pragma unroll
  for (int q = 0; q < 4; ++q) {
    int chunk = q * 512 + tid;
    int row = chunk >> 3, c = chunk & 7;
    sA[q] = (size_t)(rowA0 + row) * ldA + ((c ^ (row & 7)) << 3);
    dA[q] = chunk * 8;
  }
  size_t sB[2]; int dB[2];
#pragma unroll
  for (int q = 0; q < 2; ++q) {
    int chunk = q * 512 + tid;
    int row = chunk >> 3, c = chunk & 7;
    sB[q] = (size_t)(rowB0 + row) * ldB + ((c ^ (row & 7)) << 3);
    dB[q] = B_OFF + chunk * 8;
  }

  int aO[2][4], bO[2][4];
#pragma unroll
  for (int kk = 0; kk < 2; ++kk) {
#pragma unroll
    for (int i = 0; i < 4; ++i) {
      int rowA = wr * 64 + i * 16 + fr;
      aO[kk][i] = rowA * 64 + (((kk * 4 + fq) ^ (rowA & 7)) << 3);
      int rowB = wc * 64 + i * 16 + fr;
      bO[kk][i] = B_OFF + rowB * 64 + (((kk * 4 + fq) ^ (rowB & 7)) << 3);
    }
  }

#pragma unroll
  for (int i = 0; i < 4; ++i)
#pragma unroll
    for (int j = 0; j < 4; ++j) acc[i][j] = (f32x4){0.f, 0.f, 0.f, 0.f};

#pragma unroll
  for (int q = 0; q < 4; ++q) gload_lds16(A + sA[q], lds + dA[q]);
#pragma unroll
  for (int q = 0; q < 2; ++q) gload_lds16(B + sB[q], lds + dB[q]);
#pragma unroll
  for (int q = 0; q < 4; ++q) gload_lds16(A + sA[q] + 64, lds + BUF_US + dA[q]);
#pragma unroll
  for (int q = 0; q < 2; ++q) gload_lds16(B + sB[q] + 64, lds + BUF_US + dB[q]);

  int bi = 0, bs = 2;
  for (int kt = 0; kt < nkt; ++kt) {
    if (kt == nkt - 1) {
      asm volatile("s_waitcnt vmcnt(0)" ::: "memory");
    } else {
      asm volatile("s_waitcnt vmcnt(6)" ::: "memory");
    }
    __builtin_amdgcn_s_barrier();
    __builtin_amdgcn_sched_barrier(0);

    if (kt + 2 < nkt) {
      const int k0 = (kt + 2) * 64;
      unsigned short* tb = lds + bs * BUF_US;
#pragma unroll
      for (int q = 0; q < 4; ++q) gload_lds16(A + sA[q] + k0, tb + dA[q]);
#pragma unroll
      for (int q = 0; q < 2; ++q) gload_lds16(B + sB[q] + k0, tb + dB[q]);
    }

    const unsigned short* cb = lds + bi * BUF_US;
#pragma unroll
    for (int kk = 0; kk < 2; ++kk) {
      bf16x8 a[4], b[4];
#pragma unroll
      for (int i = 0; i < 4; ++i) a[i] = *reinterpret_cast<const bf16x8*>(cb + aO[kk][i]);
#pragma unroll
      for (int j = 0; j < 4; ++j) b[j] = *reinterpret_cast<const bf16x8*>(cb + bO[kk][j]);
      __builtin_amdgcn_s_setprio(1);
#pragma unroll
      for (int i = 0; i < 4; ++i)
#pragma unroll
        for (int j = 0; j < 4; ++j)
          acc[i][j] = __builtin_amdgcn_mfma_f32_16x16x32_bf16(a[i], b[j], acc[i][j], 0, 0, 0);
      __builtin_amdgcn_s_setprio(0);
    }

    bi = (bi == 2) ? 0 : bi + 1;
    bs = (bs == 2) ? 0 : bs + 1;
  }
}

__global__ __launch_bounds__(512, 2) void k_gemm2(
    const unsigned short* __restrict__ inter,  // [NT][NK2] bf16
    const unsigned short* __restrict__ W2t,    // [NH][NK2] bf16
    float* __restrict__ out) {                 // [NT][NH] f32
  __shared__ unsigned short lds[3 * BUF_US];
  const int t0 = blockIdx.y * 256;
  const int h0 = blockIdx.x * 128;
  f32x4 acc[4][4];
  gemm_core(inter, NK2, t0, W2t, NK2, h0, NK2 / 64, lds, acc);

  const int tid = threadIdx.x, lane = tid & 63, wave = tid >> 6;
  const int wr = wave >> 1, wc = wave & 1, fr = lane & 15, fq = lane >> 4;
  const int rowBase = t0 + wr * 64 + fq * 4;
#pragma unroll
  for (int i = 0; i < 4; ++i)
#pragma unroll
    for (int j = 0; j < 4; ++j)
#pragma unroll
      for (int r = 0; r < 4; ++r)
        out[(size_t)(rowBase + i * 16 + r) * NH + h0 + wc * 64 + j * 16 + fr] =
            acc[i][j][r];
}

extern "C" void kernel_launch(void* const* d_in, const int* in_sizes, int n_in,
                              void* d_out, int out_size, void* d_ws, size_t ws_size,
                              hipStream_t stream) {
  const float* x = (const float*)d_in[0];    // [NT][NH]
  const float* rw = (const float*)d_in[1];   // [NT][NE]
  // d_in[2] router_indices: unused by reference (dense all-experts)
  const float* w1 = (const float*)d_in[3];   // [NE][NH][2*NI]
  const float* w2 = (const float*)d_in[4];   // [NE][NI][NH]
  float* out = (float*)d_out;

  char* ws = (char*)d_ws;
  // ws layout (bf16): Xb 16MB | W1t 48MB | W2t 24MB | inter 48MB  = 136 MiB
  unsigned short* Xb = (unsigned short*)ws;                               // [NT][NH]
  unsigned short* W1t = (unsigned short*)(ws + 16777216);                 // [NE][1536perm][NH]
  unsigned short* W2t = (unsigned short*)(ws + 16777216 + 50331648);      // [NH][NK2]
  unsigned short* inter = (unsigned short*)(ws + 16777216 + 50331648 + 25165824); // [NT][NK2]

  // 1) convert x
  k_cvt<<<dim3((NT * NH) / (256 * 8)), dim3(256), 0, stream>>>(x, Xb, (long)NT * NH);
  // 2) W1 [E][H][2I] -> W1t [E][perm(2I)][H], gate/up 16-interleaved
  k_transpose_cvt<<<dim3((2 * NI) / 32, NH / 32, NE), dim3(32, 8), 0, stream>>>(
      w1, W1t, NH, 2 * NI, (long)NH * 2 * NI, (long)2 * NI * NH, NH, 1);
  // 3) W2 [E][I][H] -> W2t [H][E*I]
  k_transpose_cvt<<<dim3(NH / 32, NI / 32, NE), dim3(32, 8), 0, stream>>>(
      w2, W2t, NI, NH, (long)NI * NH, (long)NI, NK2, 0);
  // 4) GEMM1 fused silu/up/rw -> inter (8-phase, one-barrier, 256x256)
  k_gemm1<<<dim3((2 * NI) / 256, NT / 256, NE), dim3(512), 0, stream>>>(Xb, W1t, rw, inter);
  // 5) GEMM2 -> out
  k_gemm2<<<dim3(NH / 128, NT / 256), dim3(512), 0, stream>>>(inter, W2t, out);
}